// Round 8
// baseline (216.597 us; speedup 1.0000x reference)
//
#include <hip/hip_runtime.h>

#define Bb 64
#define Ss 1000
#define Kk 12
#define Nn 80
#define CTERM 73.51508265637381f   // 0.5 * 80 * log(2*pi)
#define STA 84                     // fp32 LDS stride (336 B, 16B-aligned)

typedef __attribute__((ext_vector_type(8))) short short8;
typedef __attribute__((ext_vector_type(4))) float f32x4;

static __device__ __forceinline__ unsigned short f2bf(float f) {
    unsigned u = __builtin_bit_cast(unsigned, f);
    unsigned r = u + 0x7FFFu + ((u >> 16) & 1u);   // round-to-nearest-even
    return (unsigned short)(r >> 16);
}
static __device__ __forceinline__ float bf2f(unsigned short h) {
    unsigned u = ((unsigned)h) << 16;
    return __builtin_bit_cast(float, u);
}

// ============ Kernel 0: x -> bf16 hi/lo B-fragments ====================================
// Frag layout: slot = ((b*64 + sg)*3 + ks)*64 + quad*16 + n holds x[sg*16+n][32ks+8quad .. +7]
__global__ __launch_bounds__(256) void xprep_kernel(
    const float* __restrict__ x, uint4* __restrict__ Xh, uint4* __restrict__ Xl)
{
    const int b   = blockIdx.x;
    const int cid = blockIdx.y * 256 + threadIdx.x;   // chunk id: 1000 s x 10 chunks
    if (cid >= 10000) return;
    const int s  = cid / 10, ch = cid - 10 * s;
    const int k0 = 8 * ch;
    const float* xp = x + ((size_t)b * Ss + s) * Nn + k0;
    float4 f0 = *(const float4*)xp;
    float4 f1 = *(const float4*)(xp + 4);
    float d[8] = {f0.x, f0.y, f0.z, f0.w, f1.x, f1.y, f1.z, f1.w};
    unsigned hh[8], lo[8];
    #pragma unroll
    for (int j = 0; j < 8; ++j) {
        unsigned short h = f2bf(d[j]);
        hh[j] = h; lo[j] = f2bf(d[j] - bf2f(h));
    }
    const int ks = k0 >> 5, quad = (k0 >> 3) & 3;
    const size_t slot = ((size_t)(b * 64 + (s >> 4)) * 3 + ks) * 64 + quad * 16 + (s & 15);
    Xh[slot] = make_uint4(hh[0]|(hh[1]<<16), hh[2]|(hh[3]<<16), hh[4]|(hh[5]<<16), hh[6]|(hh[7]<<16));
    Xl[slot] = make_uint4(lo[0]|(lo[1]<<16), lo[2]|(lo[3]<<16), lo[4]|(lo[5]<<16), lo[6]|(lo[7]<<16));
}

// ============ Kernel 1: rank-4 Cholesky + inversion, single 27KB LDS array =============
// Lower triangle of Ls: scaled L. Upper incl diag (written in phase B): acc[c][i]=W[i][c].
__global__ __launch_bounds__(64) void prep_kernel(
    const float* __restrict__ sigma, const float* __restrict__ mu,
    uint4* __restrict__ wsWh, uint4* __restrict__ wsWl,   // [768][800] uint4 fragments
    float* __restrict__ wsV, float* __restrict__ wsL)
{
    __shared__ float Ls[Nn * STA];   // 26.9 KB (no LT mirror -> 5 blocks/CU)
    __shared__ float invd[Nn];
    __shared__ float mus[Nn];

    const int bk = blockIdx.x;
    const int l  = threadIdx.x;
    const int r2 = l + 64;

    // ---- stage sigma ----
    const float4* sp4 = (const float4*)(sigma + (size_t)bk * Nn * Nn);
    #pragma unroll
    for (int it = 0; it < 25; ++it) {
        int ci = l + 64 * it;
        float4 v = sp4[ci];
        int r = ci / 20, c4 = 4 * (ci - 20 * r);
        *(float4*)&Ls[r * STA + c4] = v;
    }
    mus[l] = mu[(size_t)bk * Nn + l];
    if (l < 16) mus[r2] = mu[(size_t)bk * Nn + r2];
    __syncthreads();
    Ls[l * STA + l] += 1e-5f;
    if (l < 16) Ls[r2 * STA + r2] += 1e-5f;
    __syncthreads();

    // ---- Phase A: blocked Cholesky (rank-4 panels); row-slice broadcasts, no LT ----
    float ldacc = 0.0f;
    for (int p = 0; p < 20; ++p) {
        const int j0 = 4 * p;
        float B00 = Ls[j0*STA+j0];
        float B10 = Ls[(j0+1)*STA+j0], B11 = Ls[(j0+1)*STA+j0+1];
        float B20 = Ls[(j0+2)*STA+j0], B21 = Ls[(j0+2)*STA+j0+1], B22 = Ls[(j0+2)*STA+j0+2];
        float B30 = Ls[(j0+3)*STA+j0], B31 = Ls[(j0+3)*STA+j0+1], B32 = Ls[(j0+3)*STA+j0+2], B33 = Ls[(j0+3)*STA+j0+3];
        float rv0 = rsqrtf(B00);
        float l10 = B10*rv0, l20 = B20*rv0, l30 = B30*rv0;
        float t11 = fmaf(-l10,l10,B11);                    float rv1 = rsqrtf(t11);
        float l21 = fmaf(-l20,l10,B21)*rv1;
        float l31 = fmaf(-l30,l10,B31)*rv1;
        float t22 = fmaf(-l21,l21,fmaf(-l20,l20,B22));     float rv2 = rsqrtf(t22);
        float l32 = fmaf(-l31,l21,fmaf(-l30,l20,B32))*rv2;
        float t33 = fmaf(-l32,l32,fmaf(-l31,l31,fmaf(-l30,l30,B33)));
        float rv3 = rsqrtf(t33);
        ldacc += 0.5f * (logf(B00) + logf(t11) + logf(t22) + logf(t33));
        if (l == 0) { invd[j0]=rv0; invd[j0+1]=rv1; invd[j0+2]=rv2; invd[j0+3]=rv3; }

        float b0=0.f,b1=0.f,b2=0.f,b3=0.f, c0=0.f,c1=0.f,c2=0.f,c3=0.f;
        const bool a1 = (l >= j0);
        const bool a2 = (l < 16) && (r2 >= j0);
        if (a1) {
            float4 a = *(float4*)&Ls[l * STA + j0];
            b0 = a.x * rv0;
            b1 = fmaf(-l10, b0, a.y) * rv1;
            b2 = fmaf(-l21, b1, fmaf(-l20, b0, a.z)) * rv2;
            b3 = fmaf(-l32, b2, fmaf(-l31, b1, fmaf(-l30, b0, a.w))) * rv3;
            *(float4*)&Ls[l * STA + j0] = make_float4(b0, b1, b2, b3);
        }
        if (a2) {
            float4 a = *(float4*)&Ls[r2 * STA + j0];
            c0 = a.x * rv0;
            c1 = fmaf(-l10, c0, a.y) * rv1;
            c2 = fmaf(-l21, c1, fmaf(-l20, c0, a.z)) * rv2;
            c3 = fmaf(-l32, c2, fmaf(-l31, c1, fmaf(-l30, c0, a.w))) * rv3;
            *(float4*)&Ls[r2 * STA + j0] = make_float4(c0, c1, c2, c3);
        }
        __syncthreads();

        // rank-4 trailing update; reads = broadcast row slices L~[4g+e][j0:j0+4)
        const bool u1 = (l >= j0 + 4);
        const bool u2 = (l < 16) && (r2 >= j0 + 4);
        #pragma unroll 2
        for (int g = p + 1; g < 20; ++g) {
            float4 q0 = *(const float4*)&Ls[(4*g+0)*STA + j0];
            float4 q1 = *(const float4*)&Ls[(4*g+1)*STA + j0];
            float4 q2 = *(const float4*)&Ls[(4*g+2)*STA + j0];
            float4 q3 = *(const float4*)&Ls[(4*g+3)*STA + j0];
            if (u1) {
                float4 t = *(float4*)&Ls[l * STA + 4*g];
                t.x = fmaf(-b0,q0.x, fmaf(-b1,q0.y, fmaf(-b2,q0.z, fmaf(-b3,q0.w, t.x))));
                t.y = fmaf(-b0,q1.x, fmaf(-b1,q1.y, fmaf(-b2,q1.z, fmaf(-b3,q1.w, t.y))));
                t.z = fmaf(-b0,q2.x, fmaf(-b1,q2.y, fmaf(-b2,q2.z, fmaf(-b3,q2.w, t.z))));
                t.w = fmaf(-b0,q3.x, fmaf(-b1,q3.y, fmaf(-b2,q3.z, fmaf(-b3,q3.w, t.w))));
                *(float4*)&Ls[l * STA + 4*g] = t;
            }
            if (u2) {
                float4 t = *(float4*)&Ls[r2 * STA + 4*g];
                t.x = fmaf(-c0,q0.x, fmaf(-c1,q0.y, fmaf(-c2,q0.z, fmaf(-c3,q0.w, t.x))));
                t.y = fmaf(-c0,q1.x, fmaf(-c1,q1.y, fmaf(-c2,q1.z, fmaf(-c3,q1.w, t.y))));
                t.z = fmaf(-c0,q2.x, fmaf(-c1,q2.y, fmaf(-c2,q2.z, fmaf(-c3,q2.w, t.z))));
                t.w = fmaf(-c0,q3.x, fmaf(-c1,q3.y, fmaf(-c2,q3.z, fmaf(-c3,q3.w, t.w))));
                *(float4*)&Ls[r2 * STA + 4*g] = t;
            }
        }
        __syncthreads();
    }
    if (l == 0) wsL[bk] = ldacc;

    // ---- Phase B: rank-4 inversion into the UPPER triangle (incl diag); no barriers ----
    {
        int gd1 = l >> 2;
        #pragma unroll
        for (int e = 0; e < 4; ++e) { int i = 4*gd1 + e; if (i >= l) Ls[l*STA + i] = (i == l) ? 1.f : 0.f; }
        for (int g = gd1 + 1; g < 20; ++g) *(float4*)&Ls[l*STA + 4*g] = make_float4(0,0,0,0);
        if (l < 16) {
            int gd2 = r2 >> 2;
            #pragma unroll
            for (int e = 0; e < 4; ++e) { int i = 4*gd2 + e; if (i >= r2) Ls[r2*STA + i] = (i == r2) ? 1.f : 0.f; }
            for (int g = gd2 + 1; g < 20; ++g) *(float4*)&Ls[r2*STA + 4*g] = make_float4(0,0,0,0);
        }
    }

    for (int p = 0; p < 20; ++p) {
        const int i0 = 4 * p;
        float m10 = Ls[(i0+1)*STA + i0];
        float m20 = Ls[(i0+2)*STA + i0];
        float m30 = Ls[(i0+3)*STA + i0];
        float m21 = Ls[(i0+2)*STA + i0+1];
        float m31 = Ls[(i0+3)*STA + i0+1];
        float m32 = Ls[(i0+3)*STA + i0+2];
        float4 iv = *(const float4*)&invd[i0];
        float w0=0.f,w1=0.f,w2=0.f,w3=0.f, v0=0.f,v1=0.f,v2=0.f,v3=0.f;
        const bool b1a = (i0 + 3 >= l);
        const bool b2a = (l < 16) && (i0 + 3 >= r2);
        if (b1a) {
            float4 a = *(float4*)&Ls[l * STA + i0];
            float a0 = (i0   >= l) ? a.x : 0.f;
            float a1_ = (i0+1 >= l) ? a.y : 0.f;
            float a2_ = (i0+2 >= l) ? a.z : 0.f;
            float a3_ = (i0+3 >= l) ? a.w : 0.f;
            w0 = a0 * iv.x;
            w1 = fmaf(-w0, m10, a1_) * iv.y;
            w2 = fmaf(-w1, m21, fmaf(-w0, m20, a2_)) * iv.z;
            w3 = fmaf(-w2, m32, fmaf(-w1, m31, fmaf(-w0, m30, a3_))) * iv.w;
            if (l <= i0) {
                *(float4*)&Ls[l * STA + i0] = make_float4(w0, w1, w2, w3);
            } else {
                if (i0   >= l) Ls[l*STA + i0  ] = w0;
                if (i0+1 >= l) Ls[l*STA + i0+1] = w1;
                if (i0+2 >= l) Ls[l*STA + i0+2] = w2;
                if (i0+3 >= l) Ls[l*STA + i0+3] = w3;
            }
        }
        if (b2a) {
            float4 a = *(float4*)&Ls[r2 * STA + i0];
            float a0 = (i0   >= r2) ? a.x : 0.f;
            float a1_ = (i0+1 >= r2) ? a.y : 0.f;
            float a2_ = (i0+2 >= r2) ? a.z : 0.f;
            float a3_ = (i0+3 >= r2) ? a.w : 0.f;
            v0 = a0 * iv.x;
            v1 = fmaf(-v0, m10, a1_) * iv.y;
            v2 = fmaf(-v1, m21, fmaf(-v0, m20, a2_)) * iv.z;
            v3 = fmaf(-v2, m32, fmaf(-v1, m31, fmaf(-v0, m30, a3_))) * iv.w;
            if (r2 <= i0) {
                *(float4*)&Ls[r2 * STA + i0] = make_float4(v0, v1, v2, v3);
            } else {
                if (i0   >= r2) Ls[r2*STA + i0  ] = v0;
                if (i0+1 >= r2) Ls[r2*STA + i0+1] = v1;
                if (i0+2 >= r2) Ls[r2*STA + i0+2] = v2;
                if (i0+3 >= r2) Ls[r2*STA + i0+3] = v3;
            }
        }
        if (b1a | b2a) {
            #pragma unroll 2
            for (int g = p + 1; g < 20; ++g) {
                float4 q0 = *(const float4*)&Ls[(4*g+0)*STA + i0];
                float4 q1 = *(const float4*)&Ls[(4*g+1)*STA + i0];
                float4 q2 = *(const float4*)&Ls[(4*g+2)*STA + i0];
                float4 q3 = *(const float4*)&Ls[(4*g+3)*STA + i0];
                if (b1a) {
                    float4 t = *(float4*)&Ls[l * STA + 4*g];
                    t.x = fmaf(-w0,q0.x, fmaf(-w1,q0.y, fmaf(-w2,q0.z, fmaf(-w3,q0.w, t.x))));
                    t.y = fmaf(-w0,q1.x, fmaf(-w1,q1.y, fmaf(-w2,q1.z, fmaf(-w3,q1.w, t.y))));
                    t.z = fmaf(-w0,q2.x, fmaf(-w1,q2.y, fmaf(-w2,q2.z, fmaf(-w3,q2.w, t.z))));
                    t.w = fmaf(-w0,q3.x, fmaf(-w1,q3.y, fmaf(-w2,q3.z, fmaf(-w3,q3.w, t.w))));
                    *(float4*)&Ls[l * STA + 4*g] = t;
                }
                if (b2a) {
                    float4 t = *(float4*)&Ls[r2 * STA + 4*g];
                    t.x = fmaf(-v0,q0.x, fmaf(-v1,q0.y, fmaf(-v2,q0.z, fmaf(-v3,q0.w, t.x))));
                    t.y = fmaf(-v0,q1.x, fmaf(-v1,q1.y, fmaf(-v2,q1.z, fmaf(-v3,q1.w, t.y))));
                    t.z = fmaf(-v0,q2.x, fmaf(-v1,q2.y, fmaf(-v2,q2.z, fmaf(-v3,q2.w, t.z))));
                    t.w = fmaf(-v0,q3.x, fmaf(-v1,q3.y, fmaf(-v2,q3.z, fmaf(-v3,q3.w, t.w))));
                    *(float4*)&Ls[r2 * STA + 4*g] = t;
                }
            }
        }
    }
    __syncthreads();

    // ---- Phase C: v = W*mu; fragment pack (masked reads: W[m][k]=acc[k][m], m>=k) ----
    {
        float s1 = 0.f, s2 = 0.f;
        #pragma unroll 4
        for (int c = 0; c < Nn; ++c) {
            float mc = mus[c];
            float wa = (c <= l)  ? Ls[c * STA + l]  : 0.f;
            s1 = fmaf(wa, mc, s1);
            if (l < 16) {
                float wb = (c <= r2) ? Ls[c * STA + r2] : 0.f;
                s2 = fmaf(wb, mc, s2);
            }
        }
        wsV[(size_t)bk * Nn + l] = s1;
        if (l < 16) wsV[(size_t)bk * Nn + r2] = s2;
    }
    const int n = l & 15, quad = l >> 4;
    uint4* ph = wsWh + (size_t)bk * 800;
    uint4* pq = wsWl + (size_t)bk * 800;
    #pragma unroll
    for (int f = 0; f < 10; ++f) {
        int ks = f / 5, mt = f - 5 * ks;
        int m = 16 * mt + n, kb = 32 * ks + 8 * quad;
        unsigned hh[8], lo[8];
        #pragma unroll
        for (int j = 0; j < 8; ++j) {
            int kc = kb + j;
            float w = (m >= kc) ? Ls[kc * STA + m] : 0.f;
            unsigned short h = f2bf(w);
            hh[j] = h; lo[j] = f2bf(w - bf2f(h));
        }
        ph[f*64 + l] = make_uint4(hh[0]|(hh[1]<<16), hh[2]|(hh[3]<<16), hh[4]|(hh[5]<<16), hh[6]|(hh[7]<<16));
        pq[f*64 + l] = make_uint4(lo[0]|(lo[1]<<16), lo[2]|(lo[3]<<16), lo[4]|(lo[5]<<16), lo[6]|(lo[7]<<16));
    }
    if (quad < 2) {
        #pragma unroll
        for (int mt = 0; mt < 5; ++mt) {
            int m = 16 * mt + n, kb = 64 + 8 * quad;
            unsigned hh[8], lo[8];
            #pragma unroll
            for (int j = 0; j < 8; ++j) {
                int kc = kb + j;
                float w = (m >= kc) ? Ls[kc * STA + m] : 0.f;
                unsigned short h = f2bf(w);
                hh[j] = h; lo[j] = f2bf(w - bf2f(h));
            }
            ph[640 + mt*32 + l] = make_uint4(hh[0]|(hh[1]<<16), hh[2]|(hh[3]<<16), hh[4]|(hh[5]<<16), hh[6]|(hh[7]<<16));
            pq[640 + mt*32 + l] = make_uint4(lo[0]|(lo[1]<<16), lo[2]|(lo[3]<<16), lo[4]|(lo[5]<<16), lo[6]|(lo[7]<<16));
        }
    }
}

// ============ Kernel 2 (full tier): block=(b,k); W in regs once; s-tiles inner =========
__global__ __launch_bounds__(256) void ll_kernel2(
    const uint4* __restrict__ Xh, const uint4* __restrict__ Xl,
    const uint4* __restrict__ wsWh, const uint4* __restrict__ wsWl,
    const float* __restrict__ wsV, const float* __restrict__ wsL,
    float* __restrict__ out)
{
    const int b = blockIdx.x;        // linear id = b + 64*k -> all k-blocks of b on same XCD
    const int k = blockIdx.y;
    const int bk = b * Kk + k;
    const int tid = threadIdx.x;
    const int wv = tid >> 6, lane = tid & 63;
    const int n = lane & 15, quad = lane >> 4;

    // W fragments resident in registers for the whole block
    const uint4* ah_p = wsWh + (size_t)bk * 800;
    const uint4* al_p = wsWl + (size_t)bk * 800;
    short8 WH[15], WL[15];
    #pragma unroll
    for (int f = 0; f < 10; ++f) {
        WH[f] = __builtin_bit_cast(short8, ah_p[f*64 + lane]);
        WL[f] = __builtin_bit_cast(short8, al_p[f*64 + lane]);
    }
    #pragma unroll
    for (int mt = 0; mt < 5; ++mt) {
        uint4 zh = make_uint4(0,0,0,0), zl = make_uint4(0,0,0,0);
        if (quad < 2) { zh = ah_p[640 + mt*32 + lane]; zl = al_p[640 + mt*32 + lane]; }
        WH[10 + mt] = __builtin_bit_cast(short8, zh);
        WL[10 + mt] = __builtin_bit_cast(short8, zl);
    }
    const float ld = wsL[bk];
    f32x4 vf[5];
    #pragma unroll
    for (int mt = 0; mt < 5; ++mt)
        vf[mt] = *(const f32x4*)&wsV[(size_t)bk * Nn + 16*mt + 4*quad];

    for (int st = 0; st < 8; ++st) {
        const int sg0 = st * 8 + wv * 2;
        short8 bh[2][3], bl[2][3];
        #pragma unroll
        for (int t = 0; t < 2; ++t)
            #pragma unroll
            for (int ks = 0; ks < 3; ++ks) {
                size_t base = ((size_t)(b * 64 + sg0 + t) * 3 + ks) * 64 + lane;
                bh[t][ks] = __builtin_bit_cast(short8, Xh[base]);
                bl[t][ks] = __builtin_bit_cast(short8, Xl[base]);
            }

        f32x4 acc[2][5];
        #pragma unroll
        for (int t = 0; t < 2; ++t)
            #pragma unroll
            for (int mt = 0; mt < 5; ++mt) acc[t][mt] = (f32x4){0.f,0.f,0.f,0.f};

        #pragma unroll
        for (int ks = 0; ks < 3; ++ks) {
            #pragma unroll
            for (int mt = 0; mt < 5; ++mt) {
                const int f = (ks < 2) ? (ks*5 + mt) : (10 + mt);
                #pragma unroll
                for (int t = 0; t < 2; ++t) {
                    acc[t][mt] = __builtin_amdgcn_mfma_f32_16x16x32_bf16(WH[f], bh[t][ks], acc[t][mt], 0, 0, 0);
                    acc[t][mt] = __builtin_amdgcn_mfma_f32_16x16x32_bf16(WL[f], bh[t][ks], acc[t][mt], 0, 0, 0);
                    acc[t][mt] = __builtin_amdgcn_mfma_f32_16x16x32_bf16(WH[f], bl[t][ks], acc[t][mt], 0, 0, 0);
                }
            }
        }

        #pragma unroll
        for (int t = 0; t < 2; ++t) {
            float q2 = 0.f;
            #pragma unroll
            for (int mt = 0; mt < 5; ++mt)
                #pragma unroll
                for (int r = 0; r < 4; ++r) {
                    float y = acc[t][mt][r] - vf[mt][r];
                    q2 = fmaf(y, y, q2);
                }
            q2 += __shfl_xor(q2, 16, 64);
            q2 += __shfl_xor(q2, 32, 64);
            int gs = st * 128 + wv * 32 + 16 * t + n;
            if (lane < 16 && gs < Ss)
                out[((size_t)b * Ss + gs) * Kk + k] = -0.5f * q2 - ld - CTERM;
        }
    }
}

// ============ Kernel 2 (mid tier, R7): zero-LDS MFMA with in-kernel x conversion =======
__global__ __launch_bounds__(256) void ll_kernel(
    const float* __restrict__ x,
    const uint4* __restrict__ wsWh, const uint4* __restrict__ wsWl,
    const float* __restrict__ wsV, const float* __restrict__ wsL,
    float* __restrict__ out)
{
    const int b    = blockIdx.x;
    const int st   = blockIdx.y;
    const int tid  = threadIdx.x;
    const int wv   = tid >> 6, lane = tid & 63;
    const int n    = lane & 15, quad = lane >> 4;
    const int sbase = st * 128 + wv * 32;

    short8 xh[2][3], xl[2][3];
    #pragma unroll
    for (int t = 0; t < 2; ++t) {
        int gs = sbase + 16 * t + n;
        #pragma unroll
        for (int ks = 0; ks < 3; ++ks) {
            int kb = 32 * ks + 8 * quad;
            float d[8] = {0.f,0.f,0.f,0.f,0.f,0.f,0.f,0.f};
            if (gs < Ss && kb < Nn) {
                const float* xp = x + ((size_t)b * Ss + gs) * Nn + kb;
                float4 f0 = *(const float4*)xp;
                float4 f1 = *(const float4*)(xp + 4);
                d[0]=f0.x; d[1]=f0.y; d[2]=f0.z; d[3]=f0.w;
                d[4]=f1.x; d[5]=f1.y; d[6]=f1.z; d[7]=f1.w;
            }
            short8 h, lo2;
            #pragma unroll
            for (int j = 0; j < 8; ++j) {
                unsigned short hv = f2bf(d[j]);
                h[j]   = (short)hv;
                lo2[j] = (short)f2bf(d[j] - bf2f(hv));
            }
            xh[t][ks] = h; xl[t][ks] = lo2;
        }
    }

    for (int k = 0; k < Kk; ++k) {
        const int bk = b * Kk + k;
        const uint4* ah_p = wsWh + (size_t)bk * 800;
        const uint4* al_p = wsWl + (size_t)bk * 800;

        f32x4 acc[2][5];
        #pragma unroll
        for (int t = 0; t < 2; ++t)
            #pragma unroll
            for (int mt = 0; mt < 5; ++mt) acc[t][mt] = (f32x4){0.f,0.f,0.f,0.f};

        #pragma unroll
        for (int ks = 0; ks < 3; ++ks) {
            short8 ah[5], al[5];
            if (ks < 2) {
                #pragma unroll
                for (int mt = 0; mt < 5; ++mt) {
                    ah[mt] = __builtin_bit_cast(short8, ah_p[(ks*5 + mt)*64 + lane]);
                    al[mt] = __builtin_bit_cast(short8, al_p[(ks*5 + mt)*64 + lane]);
                }
            } else {
                #pragma unroll
                for (int mt = 0; mt < 5; ++mt) {
                    uint4 zh = make_uint4(0,0,0,0), zl = make_uint4(0,0,0,0);
                    if (quad < 2) {
                        zh = ah_p[640 + mt*32 + lane];
                        zl = al_p[640 + mt*32 + lane];
                    }
                    ah[mt] = __builtin_bit_cast(short8, zh);
                    al[mt] = __builtin_bit_cast(short8, zl);
                }
            }
            #pragma unroll
            for (int mt = 0; mt < 5; ++mt)
                #pragma unroll
                for (int t = 0; t < 2; ++t) {
                    acc[t][mt] = __builtin_amdgcn_mfma_f32_16x16x32_bf16(ah[mt], xh[t][ks], acc[t][mt], 0, 0, 0);
                    acc[t][mt] = __builtin_amdgcn_mfma_f32_16x16x32_bf16(al[mt], xh[t][ks], acc[t][mt], 0, 0, 0);
                    acc[t][mt] = __builtin_amdgcn_mfma_f32_16x16x32_bf16(ah[mt], xl[t][ks], acc[t][mt], 0, 0, 0);
                }
        }

        float ld = wsL[bk];
        f32x4 vf[5];
        #pragma unroll
        for (int mt = 0; mt < 5; ++mt)
            vf[mt] = *(const f32x4*)&wsV[(size_t)bk * Nn + 16*mt + 4*quad];
        #pragma unroll
        for (int t = 0; t < 2; ++t) {
            float q2 = 0.f;
            #pragma unroll
            for (int mt = 0; mt < 5; ++mt)
                #pragma unroll
                for (int r = 0; r < 4; ++r) {
                    float y = acc[t][mt][r] - vf[mt][r];
                    q2 = fmaf(y, y, q2);
                }
            q2 += __shfl_xor(q2, 16, 64);
            q2 += __shfl_xor(q2, 32, 64);
            int gs = sbase + 16 * t + n;
            if (lane < 16 && gs < Ss)
                out[((size_t)b * Ss + gs) * Kk + k] = -0.5f * q2 - ld - CTERM;
        }
    }
}

// ============ Fallback (ws too small) ==================================================
#define ST1 81
__global__ __launch_bounds__(256) void mvn_ll_fallback(
    const float* __restrict__ x, const float* __restrict__ mu,
    const float* __restrict__ sigma, float* __restrict__ out)
{
    __shared__ float Ls[Nn * ST1];
    __shared__ float invd[Nn];
    __shared__ float mus[Nn];
    __shared__ float logdet_s;

    const int bk = blockIdx.x, b = bk / Kk, k = bk - b * Kk;
    const int tid = threadIdx.x, nt = blockDim.x;

    const float* sp = sigma + (size_t)bk * Nn * Nn;
    for (int t = tid; t < Nn * Nn; t += nt) Ls[(t / Nn) * ST1 + (t % Nn)] = sp[t];
    if (tid < Nn) mus[tid] = mu[(size_t)bk * Nn + tid];
    __syncthreads();
    if (tid < Nn) Ls[tid * ST1 + tid] += 1e-5f;
    __syncthreads();
    for (int j = 0; j < Nn; ++j) {
        if (tid == 0) {
            float d = sqrtf(Ls[j * ST1 + j]);
            Ls[j * ST1 + j] = d; invd[j] = 1.0f / d;
        }
        __syncthreads();
        const float inv = invd[j];
        for (int i = j + 1 + tid; i < Nn; i += nt) Ls[i * ST1 + j] *= inv;
        __syncthreads();
        for (int t = tid; t < Nn * Nn; t += nt) {
            int r = t / Nn, c = t % Nn;
            if (r > j && c > j && c <= r)
                Ls[r * ST1 + c] -= Ls[r * ST1 + j] * Ls[c * ST1 + j];
        }
        __syncthreads();
    }
    if (tid == 0) {
        float a = 0.f; for (int j = 0; j < Nn; ++j) a += logf(Ls[j * ST1 + j]);
        logdet_s = a;
    }
    __syncthreads();
    const float ld = logdet_s;
    for (int s = tid; s < Ss; s += nt) {
        const float4* xp = (const float4*)(x + ((size_t)b * Ss + s) * Nn);
        float a[Nn];
        #pragma unroll
        for (int q = 0; q < Nn / 4; ++q) {
            float4 v = xp[q];
            a[4*q+0] = v.x - mus[4*q+0]; a[4*q+1] = v.y - mus[4*q+1];
            a[4*q+2] = v.z - mus[4*q+2]; a[4*q+3] = v.w - mus[4*q+3];
        }
        #pragma unroll
        for (int i = 0; i < Nn; ++i) {
            float t = a[i];
            #pragma unroll
            for (int j = 0; j < i; ++j) t = fmaf(-Ls[i * ST1 + j], a[j], t);
            a[i] = t * invd[i];
        }
        float quad = 0.f;
        #pragma unroll
        for (int i = 0; i < Nn; ++i) quad = fmaf(a[i], a[i], quad);
        out[((size_t)b * Ss + s) * Kk + k] = -0.5f * quad - ld - CTERM;
    }
}

extern "C" void kernel_launch(void* const* d_in, const int* in_sizes, int n_in,
                              void* d_out, int out_size, void* d_ws, size_t ws_size,
                              hipStream_t stream) {
    const float* x     = (const float*)d_in[0];
    const float* mu    = (const float*)d_in[1];
    const float* sigma = (const float*)d_in[2];
    float* out = (float*)d_out;

    const size_t nBK   = (size_t)Bb * Kk;            // 768
    const size_t nWu4  = nBK * 800;                  // W frag uint4s per array
    const size_t nXu4  = (size_t)Bb * 64 * 3 * 64;   // 786432 x-frag uint4s per array
    const size_t need_mid  = nWu4 * 16 * 2 + nBK * Nn * 4 + nBK * 4;
    const size_t need_full = need_mid + nXu4 * 16 * 2;

    if (ws_size >= need_full) {
        uint4* wsWh = (uint4*)d_ws;
        uint4* wsWl = wsWh + nWu4;
        uint4* Xh   = wsWl + nWu4;
        uint4* Xl   = Xh + nXu4;
        float* wsV  = (float*)(Xl + nXu4);
        float* wsL  = wsV + nBK * Nn;
        xprep_kernel<<<dim3(Bb, 40), dim3(256), 0, stream>>>(x, Xh, Xl);
        prep_kernel<<<dim3(Bb * Kk), dim3(64), 0, stream>>>(sigma, mu, wsWh, wsWl, wsV, wsL);
        ll_kernel2<<<dim3(Bb, Kk), dim3(256), 0, stream>>>(Xh, Xl, wsWh, wsWl, wsV, wsL, out);
    } else if (ws_size >= need_mid) {
        uint4* wsWh = (uint4*)d_ws;
        uint4* wsWl = wsWh + nWu4;
        float* wsV  = (float*)(wsWl + nWu4);
        float* wsL  = wsV + nBK * Nn;
        prep_kernel<<<dim3(Bb * Kk), dim3(64), 0, stream>>>(sigma, mu, wsWh, wsWl, wsV, wsL);
        ll_kernel<<<dim3(Bb, 8), dim3(256), 0, stream>>>(x, wsWh, wsWl, wsV, wsL, out);
    } else {
        mvn_ll_fallback<<<dim3(Bb * Kk), dim3(256), 0, stream>>>(x, mu, sigma, out);
    }
}

// Round 9
// 201.689 us; speedup vs baseline: 1.0739x; 1.0739x over previous
//
#include <hip/hip_runtime.h>

#define Bb 64
#define Ss 1000
#define Kk 12
#define Nn 80
#define CTERM 73.51508265637381f   // 0.5 * 80 * log(2*pi)
#define STA 84                     // fp32 LDS stride (336 B, 16B-aligned)

typedef __attribute__((ext_vector_type(8))) short short8;
typedef __attribute__((ext_vector_type(4))) float f32x4;

static __device__ __forceinline__ unsigned short f2bf(float f) {
    unsigned u = __builtin_bit_cast(unsigned, f);
    unsigned r = u + 0x7FFFu + ((u >> 16) & 1u);   // round-to-nearest-even
    return (unsigned short)(r >> 16);
}
static __device__ __forceinline__ float bf2f(unsigned short h) {
    unsigned u = ((unsigned)h) << 16;
    return __builtin_bit_cast(float, u);
}

// ============ Kernel 1: rank-4 Cholesky (R7 structure) + fused x->frag conversion ======
// Frag layout: frag(lane,j) = W[16mt+n][32ks+8quad+j], n=lane&15, quad=lane>>4.
// Per bk: f=0..9 (ks=0,1): f*64+lane; ks=2: 640+mt*32+lane (quad<2).
// X frag slot: ((b*64 + sg)*3 + ks)*64 + quad*16 + n  holds x[sg*16+n][32ks+8quad .. +7]
__global__ __launch_bounds__(64) void prep_kernel(
    const float* __restrict__ sigma, const float* __restrict__ mu,
    const float* __restrict__ x,
    uint4* __restrict__ wsWh, uint4* __restrict__ wsWl,   // [768][800] uint4
    float* __restrict__ wsV, float* __restrict__ wsL,
    uint4* __restrict__ Xh, uint4* __restrict__ Xl, int doX)
{
    __shared__ float Ls[Nn * STA];   // phase A: working matrix; phase B: acc (W columns)
    __shared__ float LT[Nn * Nn];    // LT[j][c] = scaled L column j (zeros c<=j)
    __shared__ float invd[Nn];
    __shared__ float mus[Nn];

    const int bk = blockIdx.x;
    const int l  = threadIdx.x;
    const int r2 = l + 64;

    // ---- stage sigma ----
    const float4* sp4 = (const float4*)(sigma + (size_t)bk * Nn * Nn);
    #pragma unroll
    for (int it = 0; it < 25; ++it) {
        int ci = l + 64 * it;
        float4 v = sp4[ci];
        int r = ci / 20, c4 = 4 * (ci - 20 * r);
        *(float4*)&Ls[r * STA + c4] = v;
    }
    mus[l] = mu[(size_t)bk * Nn + l];
    if (l < 16) mus[r2] = mu[(size_t)bk * Nn + r2];
    __syncthreads();
    Ls[l * STA + l] += 1e-5f;
    if (l < 16) Ls[r2 * STA + r2] += 1e-5f;
    __syncthreads();

    // ---- Phase A: blocked Cholesky, 4-wide panels ----
    float ldacc = 0.0f;
    for (int p = 0; p < 20; ++p) {
        const int j0 = 4 * p;
        float B00 = Ls[j0*STA+j0];
        float B10 = Ls[(j0+1)*STA+j0], B11 = Ls[(j0+1)*STA+j0+1];
        float B20 = Ls[(j0+2)*STA+j0], B21 = Ls[(j0+2)*STA+j0+1], B22 = Ls[(j0+2)*STA+j0+2];
        float B30 = Ls[(j0+3)*STA+j0], B31 = Ls[(j0+3)*STA+j0+1], B32 = Ls[(j0+3)*STA+j0+2], B33 = Ls[(j0+3)*STA+j0+3];
        float rv0 = rsqrtf(B00);
        float l10 = B10*rv0, l20 = B20*rv0, l30 = B30*rv0;
        float t11 = fmaf(-l10,l10,B11);                    float rv1 = rsqrtf(t11);
        float l21 = fmaf(-l20,l10,B21)*rv1;
        float l31 = fmaf(-l30,l10,B31)*rv1;
        float t22 = fmaf(-l21,l21,fmaf(-l20,l20,B22));     float rv2 = rsqrtf(t22);
        float l32 = fmaf(-l31,l21,fmaf(-l30,l20,B32))*rv2;
        float t33 = fmaf(-l32,l32,fmaf(-l31,l31,fmaf(-l30,l30,B33)));
        float rv3 = rsqrtf(t33);
        ldacc += 0.5f * (logf(B00) + logf(t11) + logf(t22) + logf(t33));
        if (l == 0) { invd[j0]=rv0; invd[j0+1]=rv1; invd[j0+2]=rv2; invd[j0+3]=rv3; }

        float b0=0.f,b1=0.f,b2=0.f,b3=0.f, c0=0.f,c1=0.f,c2=0.f,c3=0.f;
        const bool a1 = (l >= j0);
        const bool a2 = (l < 16) && (r2 >= j0);
        if (a1) {
            float4 a = *(float4*)&Ls[l * STA + j0];
            b0 = a.x * rv0;
            b1 = fmaf(-l10, b0, a.y) * rv1;
            b2 = fmaf(-l21, b1, fmaf(-l20, b0, a.z)) * rv2;
            b3 = fmaf(-l32, b2, fmaf(-l31, b1, fmaf(-l30, b0, a.w))) * rv3;
            *(float4*)&Ls[l * STA + j0] = make_float4(b0, b1, b2, b3);
        }
        if (a2) {
            float4 a = *(float4*)&Ls[r2 * STA + j0];
            c0 = a.x * rv0;
            c1 = fmaf(-l10, c0, a.y) * rv1;
            c2 = fmaf(-l21, c1, fmaf(-l20, c0, a.z)) * rv2;
            c3 = fmaf(-l32, c2, fmaf(-l31, c1, fmaf(-l30, c0, a.w))) * rv3;
            *(float4*)&Ls[r2 * STA + j0] = make_float4(c0, c1, c2, c3);
        }
        LT[ j0   *Nn + l] = (l  > j0  ) ? b0 : 0.f;
        LT[(j0+1)*Nn + l] = (l  > j0+1) ? b1 : 0.f;
        LT[(j0+2)*Nn + l] = (l  > j0+2) ? b2 : 0.f;
        LT[(j0+3)*Nn + l] = (l  > j0+3) ? b3 : 0.f;
        if (l < 16) {
            LT[ j0   *Nn + r2] = (r2 > j0  ) ? c0 : 0.f;
            LT[(j0+1)*Nn + r2] = (r2 > j0+1) ? c1 : 0.f;
            LT[(j0+2)*Nn + r2] = (r2 > j0+2) ? c2 : 0.f;
            LT[(j0+3)*Nn + r2] = (r2 > j0+3) ? c3 : 0.f;
        }
        __syncthreads();

        // rank-4 trailing update (cols >= j0+4)
        #pragma unroll 2
        for (int g = p + 1; g < 20; ++g) {
            float4 u0 = *(const float4*)&LT[ j0   *Nn + 4*g];
            float4 u1 = *(const float4*)&LT[(j0+1)*Nn + 4*g];
            float4 u2 = *(const float4*)&LT[(j0+2)*Nn + 4*g];
            float4 u3 = *(const float4*)&LT[(j0+3)*Nn + 4*g];
            if (a1) {
                float4 t = *(float4*)&Ls[l * STA + 4*g];
                t.x = fmaf(-b0,u0.x, fmaf(-b1,u1.x, fmaf(-b2,u2.x, fmaf(-b3,u3.x, t.x))));
                t.y = fmaf(-b0,u0.y, fmaf(-b1,u1.y, fmaf(-b2,u2.y, fmaf(-b3,u3.y, t.y))));
                t.z = fmaf(-b0,u0.z, fmaf(-b1,u1.z, fmaf(-b2,u2.z, fmaf(-b3,u3.z, t.z))));
                t.w = fmaf(-b0,u0.w, fmaf(-b1,u1.w, fmaf(-b2,u2.w, fmaf(-b3,u3.w, t.w))));
                *(float4*)&Ls[l * STA + 4*g] = t;
            }
            if (a2) {
                float4 t = *(float4*)&Ls[r2 * STA + 4*g];
                t.x = fmaf(-c0,u0.x, fmaf(-c1,u1.x, fmaf(-c2,u2.x, fmaf(-c3,u3.x, t.x))));
                t.y = fmaf(-c0,u0.y, fmaf(-c1,u1.y, fmaf(-c2,u2.y, fmaf(-c3,u3.y, t.y))));
                t.z = fmaf(-c0,u0.z, fmaf(-c1,u1.z, fmaf(-c2,u2.z, fmaf(-c3,u3.z, t.z))));
                t.w = fmaf(-c0,u0.w, fmaf(-c1,u1.w, fmaf(-c2,u2.w, fmaf(-c3,u3.w, t.w))));
                *(float4*)&Ls[r2 * STA + 4*g] = t;
            }
        }
        __syncthreads();
    }
    if (l == 0) wsL[bk] = ldacc;

    // ---- Phase B: rank-4 triangular inversion, ZERO barriers (lane-private rows) ----
    #pragma unroll
    for (int g = 0; g < 20; ++g) {
        float4 z = make_float4(0.f, 0.f, 0.f, 0.f);
        *(float4*)&Ls[l * STA + 4*g] = z;
        if (l < 16) *(float4*)&Ls[r2 * STA + 4*g] = z;
    }
    Ls[l * STA + l] = 1.0f;
    if (l < 16) Ls[r2 * STA + r2] = 1.0f;

    for (int p = 0; p < 20; ++p) {
        const int i0 = 4 * p;
        float m10 = LT[ i0   *Nn + i0+1];
        float m20 = LT[ i0   *Nn + i0+2];
        float m30 = LT[ i0   *Nn + i0+3];
        float m21 = LT[(i0+1)*Nn + i0+2];
        float m31 = LT[(i0+1)*Nn + i0+3];
        float m32 = LT[(i0+2)*Nn + i0+3];
        float4 iv = *(const float4*)&invd[i0];
        float w0=0.f,w1=0.f,w2=0.f,w3=0.f, v0=0.f,v1=0.f,v2=0.f,v3=0.f;
        const bool b1a = (i0 + 3 >= l);
        const bool b2a = (l < 16) && (i0 + 3 >= r2);
        if (b1a) {
            float4 a = *(float4*)&Ls[l * STA + i0];
            w0 = a.x * iv.x;
            w1 = fmaf(-w0, m10, a.y) * iv.y;
            w2 = fmaf(-w1, m21, fmaf(-w0, m20, a.z)) * iv.z;
            w3 = fmaf(-w2, m32, fmaf(-w1, m31, fmaf(-w0, m30, a.w))) * iv.w;
            *(float4*)&Ls[l * STA + i0] = make_float4(w0, w1, w2, w3);
        }
        if (b2a) {
            float4 a = *(float4*)&Ls[r2 * STA + i0];
            v0 = a.x * iv.x;
            v1 = fmaf(-v0, m10, a.y) * iv.y;
            v2 = fmaf(-v1, m21, fmaf(-v0, m20, a.z)) * iv.z;
            v3 = fmaf(-v2, m32, fmaf(-v1, m31, fmaf(-v0, m30, a.w))) * iv.w;
            *(float4*)&Ls[r2 * STA + i0] = make_float4(v0, v1, v2, v3);
        }
        if (b1a | b2a) {
            #pragma unroll 2
            for (int g = p + 1; g < 20; ++g) {
                float4 u0 = *(const float4*)&LT[ i0   *Nn + 4*g];
                float4 u1 = *(const float4*)&LT[(i0+1)*Nn + 4*g];
                float4 u2 = *(const float4*)&LT[(i0+2)*Nn + 4*g];
                float4 u3 = *(const float4*)&LT[(i0+3)*Nn + 4*g];
                if (b1a) {
                    float4 t = *(float4*)&Ls[l * STA + 4*g];
                    t.x = fmaf(-w0,u0.x, fmaf(-w1,u1.x, fmaf(-w2,u2.x, fmaf(-w3,u3.x, t.x))));
                    t.y = fmaf(-w0,u0.y, fmaf(-w1,u1.y, fmaf(-w2,u2.y, fmaf(-w3,u3.y, t.y))));
                    t.z = fmaf(-w0,u0.z, fmaf(-w1,u1.z, fmaf(-w2,u2.z, fmaf(-w3,u3.z, t.z))));
                    t.w = fmaf(-w0,u0.w, fmaf(-w1,u1.w, fmaf(-w2,u2.w, fmaf(-w3,u3.w, t.w))));
                    *(float4*)&Ls[l * STA + 4*g] = t;
                }
                if (b2a) {
                    float4 t = *(float4*)&Ls[r2 * STA + 4*g];
                    t.x = fmaf(-v0,u0.x, fmaf(-v1,u1.x, fmaf(-v2,u2.x, fmaf(-v3,u3.x, t.x))));
                    t.y = fmaf(-v0,u0.y, fmaf(-v1,u1.y, fmaf(-v2,u2.y, fmaf(-v3,u3.y, t.y))));
                    t.z = fmaf(-v0,u0.z, fmaf(-v1,u1.z, fmaf(-v2,u2.z, fmaf(-v3,u3.z, t.z))));
                    t.w = fmaf(-v0,u0.w, fmaf(-v1,u1.w, fmaf(-v2,u2.w, fmaf(-v3,u3.w, t.w))));
                    *(float4*)&Ls[r2 * STA + 4*g] = t;
                }
            }
        }
    }
    __syncthreads();

    // ---- Phase C: v = W*mu; fragment pack (hi/lo bf16; Ls upper holds exact zeros) ----
    {
        float s1 = 0.f, s2 = 0.f;
        #pragma unroll 4
        for (int c = 0; c < Nn; ++c) {
            float mc = mus[c];
            s1 = fmaf(Ls[c * STA + l], mc, s1);
            if (l < 16) s2 = fmaf(Ls[c * STA + r2], mc, s2);
        }
        wsV[(size_t)bk * Nn + l] = s1;
        if (l < 16) wsV[(size_t)bk * Nn + r2] = s2;
    }
    const int n = l & 15, quad = l >> 4;
    uint4* ph = wsWh + (size_t)bk * 800;
    uint4* pq = wsWl + (size_t)bk * 800;
    #pragma unroll
    for (int f = 0; f < 10; ++f) {
        int ks = f / 5, mt = f - 5 * ks;
        int m = 16 * mt + n, kb = 32 * ks + 8 * quad;
        unsigned hh[8], lo[8];
        #pragma unroll
        for (int j = 0; j < 8; ++j) {
            float w = Ls[(kb + j) * STA + m];    // = W[m][kb+j]
            unsigned short h = f2bf(w);
            hh[j] = h; lo[j] = f2bf(w - bf2f(h));
        }
        ph[f*64 + l] = make_uint4(hh[0]|(hh[1]<<16), hh[2]|(hh[3]<<16), hh[4]|(hh[5]<<16), hh[6]|(hh[7]<<16));
        pq[f*64 + l] = make_uint4(lo[0]|(lo[1]<<16), lo[2]|(lo[3]<<16), lo[4]|(lo[5]<<16), lo[6]|(lo[7]<<16));
    }
    if (quad < 2) {
        #pragma unroll
        for (int mt = 0; mt < 5; ++mt) {
            int m = 16 * mt + n, kb = 64 + 8 * quad;
            unsigned hh[8], lo[8];
            #pragma unroll
            for (int j = 0; j < 8; ++j) {
                float w = Ls[(kb + j) * STA + m];
                unsigned short h = f2bf(w);
                hh[j] = h; lo[j] = f2bf(w - bf2f(h));
            }
            ph[640 + mt*32 + l] = make_uint4(hh[0]|(hh[1]<<16), hh[2]|(hh[3]<<16), hh[4]|(hh[5]<<16), hh[6]|(hh[7]<<16));
            pq[640 + mt*32 + l] = make_uint4(lo[0]|(lo[1]<<16), lo[2]|(lo[3]<<16), lo[4]|(lo[5]<<16), lo[6]|(lo[7]<<16));
        }
    }

    // ---- Fused tail: x -> bf16 hi/lo B-fragments (fills idle issue slots) ----
    if (doX) {
        for (int it = 0; ; ++it) {
            int grp = bk + 768 * it;          // 64-lane groups, 10000 total
            if (grp >= 10000) break;
            int gcid = grp * 64 + l;          // 0..639999
            int b2  = gcid / 10000;
            int rem = gcid - b2 * 10000;
            int s   = rem / 10, ch = rem - 10 * s;
            int k0  = 8 * ch;
            const float* xp = x + ((size_t)b2 * Ss + s) * Nn + k0;
            float4 f0 = *(const float4*)xp;
            float4 f1 = *(const float4*)(xp + 4);
            float d[8] = {f0.x, f0.y, f0.z, f0.w, f1.x, f1.y, f1.z, f1.w};
            unsigned hh[8], lo[8];
            #pragma unroll
            for (int j = 0; j < 8; ++j) {
                unsigned short h = f2bf(d[j]);
                hh[j] = h; lo[j] = f2bf(d[j] - bf2f(h));
            }
            int ks = k0 >> 5, qd = (k0 >> 3) & 3;
            size_t slot = ((size_t)(b2 * 64 + (s >> 4)) * 3 + ks) * 64 + qd * 16 + (s & 15);
            Xh[slot] = make_uint4(hh[0]|(hh[1]<<16), hh[2]|(hh[3]<<16), hh[4]|(hh[5]<<16), hh[6]|(hh[7]<<16));
            Xl[slot] = make_uint4(lo[0]|(lo[1]<<16), lo[2]|(lo[3]<<16), lo[4]|(lo[5]<<16), lo[6]|(lo[7]<<16));
        }
    }
}

// ============ Kernel 2 (full tier): W frags in LDS (zero-expanded), B frags from global =
__global__ __launch_bounds__(256) void ll_kernel2(
    const uint4* __restrict__ Xh, const uint4* __restrict__ Xl,
    const uint4* __restrict__ wsWh, const uint4* __restrict__ wsWl,
    const float* __restrict__ wsV, const float* __restrict__ wsL,
    float* __restrict__ out)
{
    __shared__ uint4 WhL[960], WlL[960];   // [0..640): ks=0,1; [640..960): ks=2 expanded
    const int b = blockIdx.x;              // linear id = b + 64*k -> same-b blocks on one XCD
    const int k = blockIdx.y;
    const int bk = b * Kk + k;
    const int tid = threadIdx.x;
    const int wv = tid >> 6, lane = tid & 63;
    const int n = lane & 15, quad = lane >> 4;

    const uint4* gh = wsWh + (size_t)bk * 800;
    const uint4* gl = wsWl + (size_t)bk * 800;
    #pragma unroll
    for (int it = 0; it < 3; ++it) {
        int i = tid + 256 * it;
        if (i < 640) { WhL[i] = gh[i]; WlL[i] = gl[i]; }
    }
    #pragma unroll
    for (int it = 0; it < 2; ++it) {
        int i = tid + 256 * it;
        if (i < 320) {
            int mt = i >> 6, ln = i & 63, qd = (ln >> 4);
            uint4 vh = make_uint4(0,0,0,0), vl = make_uint4(0,0,0,0);
            if (qd < 2) { vh = gh[640 + mt*32 + ln]; vl = gl[640 + mt*32 + ln]; }
            WhL[640 + i] = vh; WlL[640 + i] = vl;
        }
    }
    __syncthreads();

    const float ld = wsL[bk];
    f32x4 vf[5];
    #pragma unroll
    for (int mt = 0; mt < 5; ++mt)
        vf[mt] = *(const f32x4*)&wsV[(size_t)bk * Nn + 16*mt + 4*quad];

    for (int st = 0; st < 8; ++st) {
        const int sg0 = st * 8 + wv * 2;
        short8 bh[2][3], bl[2][3];
        #pragma unroll
        for (int t = 0; t < 2; ++t)
            #pragma unroll
            for (int ks = 0; ks < 3; ++ks) {
                size_t base = ((size_t)(b * 64 + sg0 + t) * 3 + ks) * 64 + lane;
                bh[t][ks] = __builtin_bit_cast(short8, Xh[base]);
                bl[t][ks] = __builtin_bit_cast(short8, Xl[base]);
            }

        f32x4 acc[2][5];
        #pragma unroll
        for (int t = 0; t < 2; ++t)
            #pragma unroll
            for (int mt = 0; mt < 5; ++mt) acc[t][mt] = (f32x4){0.f,0.f,0.f,0.f};

        #pragma unroll
        for (int ks = 0; ks < 3; ++ks) {
            #pragma unroll
            for (int mt = 0; mt < 5; ++mt) {
                const int fi = (ks < 2) ? (ks*5 + mt)*64 + lane : 640 + mt*64 + lane;
                short8 wh = __builtin_bit_cast(short8, WhL[fi]);
                short8 wl = __builtin_bit_cast(short8, WlL[fi]);
                #pragma unroll
                for (int t = 0; t < 2; ++t) {
                    acc[t][mt] = __builtin_amdgcn_mfma_f32_16x16x32_bf16(wh, bh[t][ks], acc[t][mt], 0, 0, 0);
                    acc[t][mt] = __builtin_amdgcn_mfma_f32_16x16x32_bf16(wl, bh[t][ks], acc[t][mt], 0, 0, 0);
                    acc[t][mt] = __builtin_amdgcn_mfma_f32_16x16x32_bf16(wh, bl[t][ks], acc[t][mt], 0, 0, 0);
                }
            }
        }

        #pragma unroll
        for (int t = 0; t < 2; ++t) {
            float q2 = 0.f;
            #pragma unroll
            for (int mt = 0; mt < 5; ++mt)
                #pragma unroll
                for (int r = 0; r < 4; ++r) {
                    float y = acc[t][mt][r] - vf[mt][r];
                    q2 = fmaf(y, y, q2);
                }
            q2 += __shfl_xor(q2, 16, 64);
            q2 += __shfl_xor(q2, 32, 64);
            int gs = st * 128 + wv * 32 + 16 * t + n;
            if (lane < 16 && gs < Ss)
                out[((size_t)b * Ss + gs) * Kk + k] = -0.5f * q2 - ld - CTERM;
        }
    }
}

// ============ Kernel 2 (mid tier): zero-LDS MFMA with in-kernel x conversion ===========
__global__ __launch_bounds__(256) void ll_kernel(
    const float* __restrict__ x,
    const uint4* __restrict__ wsWh, const uint4* __restrict__ wsWl,
    const float* __restrict__ wsV, const float* __restrict__ wsL,
    float* __restrict__ out)
{
    const int b    = blockIdx.x;
    const int st   = blockIdx.y;
    const int tid  = threadIdx.x;
    const int wv   = tid >> 6, lane = tid & 63;
    const int n    = lane & 15, quad = lane >> 4;
    const int sbase = st * 128 + wv * 32;

    short8 xh[2][3], xl[2][3];
    #pragma unroll
    for (int t = 0; t < 2; ++t) {
        int gs = sbase + 16 * t + n;
        #pragma unroll
        for (int ks = 0; ks < 3; ++ks) {
            int kb = 32 * ks + 8 * quad;
            float d[8] = {0.f,0.f,0.f,0.f,0.f,0.f,0.f,0.f};
            if (gs < Ss && kb < Nn) {
                const float* xp = x + ((size_t)b * Ss + gs) * Nn + kb;
                float4 f0 = *(const float4*)xp;
                float4 f1 = *(const float4*)(xp + 4);
                d[0]=f0.x; d[1]=f0.y; d[2]=f0.z; d[3]=f0.w;
                d[4]=f1.x; d[5]=f1.y; d[6]=f1.z; d[7]=f1.w;
            }
            short8 h, lo2;
            #pragma unroll
            for (int j = 0; j < 8; ++j) {
                unsigned short hv = f2bf(d[j]);
                h[j]   = (short)hv;
                lo2[j] = (short)f2bf(d[j] - bf2f(hv));
            }
            xh[t][ks] = h; xl[t][ks] = lo2;
        }
    }

    for (int k = 0; k < Kk; ++k) {
        const int bk = b * Kk + k;
        const uint4* ah_p = wsWh + (size_t)bk * 800;
        const uint4* al_p = wsWl + (size_t)bk * 800;

        f32x4 acc[2][5];
        #pragma unroll
        for (int t = 0; t < 2; ++t)
            #pragma unroll
            for (int mt = 0; mt < 5; ++mt) acc[t][mt] = (f32x4){0.f,0.f,0.f,0.f};

        #pragma unroll
        for (int ks = 0; ks < 3; ++ks) {
            short8 ah[5], al[5];
            if (ks < 2) {
                #pragma unroll
                for (int mt = 0; mt < 5; ++mt) {
                    ah[mt] = __builtin_bit_cast(short8, ah_p[(ks*5 + mt)*64 + lane]);
                    al[mt] = __builtin_bit_cast(short8, al_p[(ks*5 + mt)*64 + lane]);
                }
            } else {
                #pragma unroll
                for (int mt = 0; mt < 5; ++mt) {
                    uint4 zh = make_uint4(0,0,0,0), zl = make_uint4(0,0,0,0);
                    if (quad < 2) {
                        zh = ah_p[640 + mt*32 + lane];
                        zl = al_p[640 + mt*32 + lane];
                    }
                    ah[mt] = __builtin_bit_cast(short8, zh);
                    al[mt] = __builtin_bit_cast(short8, zl);
                }
            }
            #pragma unroll
            for (int mt = 0; mt < 5; ++mt)
                #pragma unroll
                for (int t = 0; t < 2; ++t) {
                    acc[t][mt] = __builtin_amdgcn_mfma_f32_16x16x32_bf16(ah[mt], xh[t][ks], acc[t][mt], 0, 0, 0);
                    acc[t][mt] = __builtin_amdgcn_mfma_f32_16x16x32_bf16(al[mt], xh[t][ks], acc[t][mt], 0, 0, 0);
                    acc[t][mt] = __builtin_amdgcn_mfma_f32_16x16x32_bf16(ah[mt], xl[t][ks], acc[t][mt], 0, 0, 0);
                }
        }

        float ld = wsL[bk];
        f32x4 vf[5];
        #pragma unroll
        for (int mt = 0; mt < 5; ++mt)
            vf[mt] = *(const f32x4*)&wsV[(size_t)bk * Nn + 16*mt + 4*quad];
        #pragma unroll
        for (int t = 0; t < 2; ++t) {
            float q2 = 0.f;
            #pragma unroll
            for (int mt = 0; mt < 5; ++mt)
                #pragma unroll
                for (int r = 0; r < 4; ++r) {
                    float y = acc[t][mt][r] - vf[mt][r];
                    q2 = fmaf(y, y, q2);
                }
            q2 += __shfl_xor(q2, 16, 64);
            q2 += __shfl_xor(q2, 32, 64);
            int gs = sbase + 16 * t + n;
            if (lane < 16 && gs < Ss)
                out[((size_t)b * Ss + gs) * Kk + k] = -0.5f * q2 - ld - CTERM;
        }
    }
}

// ============ Fallback (ws too small) ==================================================
#define ST1 81
__global__ __launch_bounds__(256) void mvn_ll_fallback(
    const float* __restrict__ x, const float* __restrict__ mu,
    const float* __restrict__ sigma, float* __restrict__ out)
{
    __shared__ float Ls[Nn * ST1];
    __shared__ float invd[Nn];
    __shared__ float mus[Nn];
    __shared__ float logdet_s;

    const int bk = blockIdx.x, b = bk / Kk, k = bk - b * Kk;
    const int tid = threadIdx.x, nt = blockDim.x;

    const float* sp = sigma + (size_t)bk * Nn * Nn;
    for (int t = tid; t < Nn * Nn; t += nt) Ls[(t / Nn) * ST1 + (t % Nn)] = sp[t];
    if (tid < Nn) mus[tid] = mu[(size_t)bk * Nn + tid];
    __syncthreads();
    if (tid < Nn) Ls[tid * ST1 + tid] += 1e-5f;
    __syncthreads();
    for (int j = 0; j < Nn; ++j) {
        if (tid == 0) {
            float d = sqrtf(Ls[j * ST1 + j]);
            Ls[j * ST1 + j] = d; invd[j] = 1.0f / d;
        }
        __syncthreads();
        const float inv = invd[j];
        for (int i = j + 1 + tid; i < Nn; i += nt) Ls[i * ST1 + j] *= inv;
        __syncthreads();
        for (int t = tid; t < Nn * Nn; t += nt) {
            int r = t / Nn, c = t % Nn;
            if (r > j && c > j && c <= r)
                Ls[r * ST1 + c] -= Ls[r * ST1 + j] * Ls[c * ST1 + j];
        }
        __syncthreads();
    }
    if (tid == 0) {
        float a = 0.f; for (int j = 0; j < Nn; ++j) a += logf(Ls[j * ST1 + j]);
        logdet_s = a;
    }
    __syncthreads();
    const float ld = logdet_s;
    for (int s = tid; s < Ss; s += nt) {
        const float4* xp = (const float4*)(x + ((size_t)b * Ss + s) * Nn);
        float a[Nn];
        #pragma unroll
        for (int q = 0; q < Nn / 4; ++q) {
            float4 v = xp[q];
            a[4*q+0] = v.x - mus[4*q+0]; a[4*q+1] = v.y - mus[4*q+1];
            a[4*q+2] = v.z - mus[4*q+2]; a[4*q+3] = v.w - mus[4*q+3];
        }
        #pragma unroll
        for (int i = 0; i < Nn; ++i) {
            float t = a[i];
            #pragma unroll
            for (int j = 0; j < i; ++j) t = fmaf(-Ls[i * ST1 + j], a[j], t);
            a[i] = t * invd[i];
        }
        float quad = 0.f;
        #pragma unroll
        for (int i = 0; i < Nn; ++i) quad = fmaf(a[i], a[i], quad);
        out[((size_t)b * Ss + s) * Kk + k] = -0.5f * quad - ld - CTERM;
    }
}

extern "C" void kernel_launch(void* const* d_in, const int* in_sizes, int n_in,
                              void* d_out, int out_size, void* d_ws, size_t ws_size,
                              hipStream_t stream) {
    const float* x     = (const float*)d_in[0];
    const float* mu    = (const float*)d_in[1];
    const float* sigma = (const float*)d_in[2];
    float* out = (float*)d_out;

    const size_t nBK   = (size_t)Bb * Kk;            // 768
    const size_t nWu4  = nBK * 800;                  // W frag uint4s per array
    const size_t nXu4  = (size_t)Bb * 64 * 3 * 64;   // 786432 x-frag uint4s per array
    const size_t need_mid  = nWu4 * 16 * 2 + nBK * Nn * 4 + nBK * 4;
    const size_t need_full = need_mid + nXu4 * 16 * 2;

    if (ws_size >= need_full) {
        uint4* wsWh = (uint4*)d_ws;
        uint4* wsWl = wsWh + nWu4;
        uint4* Xh   = wsWl + nWu4;
        uint4* Xl   = Xh + nXu4;
        float* wsV  = (float*)(Xl + nXu4);
        float* wsL  = wsV + nBK * Nn;
        prep_kernel<<<dim3(Bb * Kk), dim3(64), 0, stream>>>(
            sigma, mu, x, wsWh, wsWl, wsV, wsL, Xh, Xl, 1);
        ll_kernel2<<<dim3(Bb, Kk), dim3(256), 0, stream>>>(Xh, Xl, wsWh, wsWl, wsV, wsL, out);
    } else if (ws_size >= need_mid) {
        uint4* wsWh = (uint4*)d_ws;
        uint4* wsWl = wsWh + nWu4;
        float* wsV  = (float*)(wsWl + nWu4);
        float* wsL  = wsV + nBK * Nn;
        prep_kernel<<<dim3(Bb * Kk), dim3(64), 0, stream>>>(
            sigma, mu, x, wsWh, wsWl, wsV, wsL, (uint4*)nullptr, (uint4*)nullptr, 0);
        ll_kernel<<<dim3(Bb, 8), dim3(256), 0, stream>>>(x, wsWh, wsWl, wsV, wsL, out);
    } else {
        mvn_ll_fallback<<<dim3(Bb * Kk), dim3(256), 0, stream>>>(x, mu, sigma, out);
    }
}